// Round 1
// baseline (294.549 us; speedup 1.0000x reference)
//
#include <hip/hip_runtime.h>
#include <stdint.h>

typedef _Float16 f16;
typedef f16 f16x8 __attribute__((ext_vector_type(8)));
typedef float f32x4 __attribute__((ext_vector_type(4)));

#define MFMA(a,b,c) __builtin_amdgcn_mfma_f32_16x16x32_f16(a, b, c, 0, 0, 0)

__device__ __forceinline__ float sigmoidf_(float z) { return 1.0f / (1.0f + __expf(-z)); }

// ---------------------------------------------------------------------------
// prep: scale[b] = sqrt(1 + count(L[b,0,:] >= 1)); convert weights to f16.
// Wcat = [Aq;Ak;Av] (192x2048). Wsm = 9 x (64x64): Aq1,Ak1,Av1,Aq5,Ak5,Av5,Ao,Ao1,Ao5
// ---------------------------------------------------------------------------
__global__ void prep_kernel(const float* __restrict__ L,
    const float* __restrict__ Aq, const float* __restrict__ Ak, const float* __restrict__ Av,
    const float* __restrict__ Aq1, const float* __restrict__ Ak1, const float* __restrict__ Av1,
    const float* __restrict__ Aq5, const float* __restrict__ Ak5, const float* __restrict__ Av5,
    const float* __restrict__ Ao, const float* __restrict__ Ao1, const float* __restrict__ Ao5,
    float* __restrict__ scale, f16* __restrict__ Wcat, f16* __restrict__ Wsm)
{
  __shared__ float r4[4];
  int blk = blockIdx.x, t = threadIdx.x;
  if (blk < 64) {
    float v = (L[blk * 512 + t] >= 1.0f) ? 1.0f : 0.0f;
    #pragma unroll
    for (int off = 32; off; off >>= 1) v += __shfl_down(v, off);
    if ((t & 63) == 0) r4[t >> 6] = v;
    __syncthreads();
    if (t == 0) scale[blk] = sqrtf(r4[0] + r4[1] + r4[2] + r4[3] + 1.0f);
  } else if (blk < 160) {
    int base = (blk - 64) * 4096;
    for (int i = 0; i < 16; i++) {
      int idx = base + t + i * 256;
      int row = idx >> 11, col = idx & 2047;
      float v = (row < 64) ? Aq[row * 2048 + col]
              : (row < 128) ? Ak[(row - 64) * 2048 + col]
              : Av[(row - 128) * 2048 + col];
      Wcat[idx] = (f16)v;
    }
  } else {
    int j = blk - 160;
    const float* s = (j == 0) ? Aq1 : (j == 1) ? Ak1 : (j == 2) ? Av1 : (j == 3) ? Aq5
                   : (j == 4) ? Ak5 : (j == 5) ? Av5 : (j == 6) ? Ao : (j == 7) ? Ao1 : Ao5;
    for (int i = 0; i < 16; i++) { int idx = t + i * 256; Wsm[j * 4096 + idx] = (f16)s[idx]; }
  }
}

// ---------------------------------------------------------------------------
// qkv1: per (b, n-group of 64): Out[n][r] = sigmoid( sum_f x[b,f,n]*Wcat[r,f] )
// r in [0,192): 0-63 -> Qt[b][n][r], 64-127 -> Kt[b][n][r-64], 128-191 -> V[b][r-128][n]
// ---------------------------------------------------------------------------
__global__ __launch_bounds__(256) void qkv1_kernel(const float* __restrict__ x,
    const f16* __restrict__ Wcat, f16* __restrict__ Qt, f16* __restrict__ Kt,
    f16* __restrict__ Vg)
{
  int b = blockIdx.y, n0 = blockIdx.x * 64;
  int t = threadIdx.x, lane = t & 63, w = t >> 6;
  int l15 = lane & 15, q = lane >> 4;
  __shared__ f16 xt[64 * 72];    // x^T tile: [n][f], stride 72
  __shared__ f16 wt[192 * 72];   // W tile: [r][f], stride 72
  f32x4 acc[4][3] = {};          // [n-tile][r-subtile], wave owns r-tiles w*3..w*3+2
  const float* xb = x + (size_t)b * 2048 * 256 + n0;
  int tn = t & 63, fp0 = t >> 6;

  for (int f0 = 0; f0 < 2048; f0 += 64) {
    // stage x (transpose fp32->f16, pair-packed b32 writes)
    #pragma unroll
    for (int rep = 0; rep < 8; rep++) {
      int fl = (fp0 + rep * 4) * 2;
      float a0 = xb[(size_t)(f0 + fl) * 256 + tn];
      float a1 = xb[(size_t)(f0 + fl + 1) * 256 + tn];
      uint32_t pk = (uint32_t)__builtin_bit_cast(uint16_t, (f16)a0)
                  | ((uint32_t)__builtin_bit_cast(uint16_t, (f16)a1) << 16);
      *(uint32_t*)&xt[tn * 72 + fl] = pk;
    }
    // stage W (already f16, b128 copies)
    #pragma unroll
    for (int i = 0; i < 6; i++) {
      int id = t + i * 256, r = id >> 3, c = id & 7;
      uint4 v = *(const uint4*)(Wcat + (size_t)r * 2048 + f0 + c * 8);
      *(uint4*)&wt[r * 72 + c * 8] = v;
    }
    __syncthreads();
    #pragma unroll
    for (int ks = 0; ks < 2; ks++) {
      int k0 = ks * 32 + q * 8;
      f16x8 af[4], bf[3];
      #pragma unroll
      for (int nt = 0; nt < 4; nt++) af[nt] = *(const f16x8*)&xt[(nt * 16 + l15) * 72 + k0];
      #pragma unroll
      for (int j = 0; j < 3; j++) bf[j] = *(const f16x8*)&wt[((w * 3 + j) * 16 + l15) * 72 + k0];
      #pragma unroll
      for (int nt = 0; nt < 4; nt++)
        #pragma unroll
        for (int j = 0; j < 3; j++)
          acc[nt][j] = MFMA(af[nt], bf[j], acc[nt][j]);
    }
    __syncthreads();
  }
  // epilogue: sigmoid + store
  #pragma unroll
  for (int nt = 0; nt < 4; nt++)
    #pragma unroll
    for (int j = 0; j < 3; j++) {
      int rr = (w * 3 + j) * 16 + l15;
      float s[4];
      #pragma unroll
      for (int reg = 0; reg < 4; reg++) s[reg] = sigmoidf_(acc[nt][j][reg]);
      int nbase = n0 + nt * 16 + q * 4;
      if (rr < 64) {
        #pragma unroll
        for (int reg = 0; reg < 4; reg++)
          Qt[(size_t)b * 16384 + (size_t)(nbase + reg) * 64 + rr] = (f16)s[reg];
      } else if (rr < 128) {
        #pragma unroll
        for (int reg = 0; reg < 4; reg++)
          Kt[(size_t)b * 16384 + (size_t)(nbase + reg) * 64 + (rr - 64)] = (f16)s[reg];
      } else {
        union { f16 h[4]; uint2 u; } pk;
        #pragma unroll
        for (int reg = 0; reg < 4; reg++) pk.h[reg] = (f16)s[reg];
        *(uint2*)(Vg + (size_t)b * 16384 + (size_t)(rr - 128) * 256 + nbase) = pk.u;
      }
    }
}

// ---------------------------------------------------------------------------
// attn_kernel: one block per batch; full 3-layer chain in LDS; final reduction.
// Layouts (f16): S1 = M^T [256][72] (layer0: V1 as [64][264]); S2 = Q^T/o^T [256][72];
// S3 = K^T [256][72]; S4 = A-chunk [256][72]; S5 = V-chunk [64][72]
// ---------------------------------------------------------------------------
__global__ __launch_bounds__(512) void attn_kernel(const float* __restrict__ x,
    const float* __restrict__ scale, const f16* __restrict__ Wsm,
    const f16* __restrict__ Qtg, const f16* __restrict__ Ktg, const f16* __restrict__ Vgg,
    float* __restrict__ out)
{
  int b = blockIdx.x;
  int t = threadIdx.x, lane = t & 63, w = t >> 6;  // 8 waves
  int l15 = lane & 15, q = lane >> 4;
  __shared__ f16 S1[256 * 72];
  __shared__ f16 S2[256 * 72];
  __shared__ f16 S3[256 * 72];
  __shared__ f16 S4[256 * 72];
  __shared__ f16 S5[64 * 72];
  __shared__ float denomS[256];
  __shared__ float red[8];

  float sinv = 1.0f / scale[b];

  // stage layer-0 inputs
  {
    const uint4* qs = (const uint4*)(Qtg + (size_t)b * 16384);
    const uint4* ks = (const uint4*)(Ktg + (size_t)b * 16384);
    const uint4* vs = (const uint4*)(Vgg + (size_t)b * 16384);
    #pragma unroll
    for (int i = 0; i < 4; i++) {
      int id = t + i * 512;
      int n = id >> 3, c = id & 7;
      *(uint4*)((char*)S2 + n * 144 + c * 16) = qs[id];
      *(uint4*)((char*)S3 + n * 144 + c * 16) = ks[id];
    }
    #pragma unroll
    for (int i = 0; i < 4; i++) {
      int id = t + i * 512;
      int r = id >> 5, c = id & 31;
      *(uint4*)((char*)S1 + r * 528 + c * 16) = vs[id];
    }
    if (t < 256) denomS[t] = 0.0f;
  }
  __syncthreads();

  #pragma unroll 1
  for (int l = 0; l < 3; l++) {
    if (l > 0) {
      // project Q^T (->S2) and K^T (->S3) from M^T (S1)
      const f16* Wq = Wsm + (size_t)((l == 1) ? 0 : 3) * 4096;
      const f16* Wk = Wsm + (size_t)((l == 1) ? 1 : 4) * 4096;
      f16x8 bq[4][2], bk[4][2];
      #pragma unroll
      for (int rt = 0; rt < 4; rt++) {
        int r = rt * 16 + l15;
        bq[rt][0] = *(const f16x8*)(Wq + r * 64 + q * 8);
        bq[rt][1] = *(const f16x8*)(Wq + r * 64 + 32 + q * 8);
        bk[rt][0] = *(const f16x8*)(Wk + r * 64 + q * 8);
        bk[rt][1] = *(const f16x8*)(Wk + r * 64 + 32 + q * 8);
      }
      #pragma unroll
      for (int half = 0; half < 2; half++) {
        int nt = 2 * w + half;
        int arow = (nt * 16 + l15) * 72;
        f16x8 af0 = *(const f16x8*)&S1[arow + q * 8];
        f16x8 af1 = *(const f16x8*)&S1[arow + 32 + q * 8];
        #pragma unroll
        for (int rt = 0; rt < 4; rt++) {
          f32x4 aq = {}; aq = MFMA(af0, bq[rt][0], aq); aq = MFMA(af1, bq[rt][1], aq);
          f32x4 akk = {}; akk = MFMA(af0, bk[rt][0], akk); akk = MFMA(af1, bk[rt][1], akk);
          int col = rt * 16 + l15;
          #pragma unroll
          for (int reg = 0; reg < 4; reg++) {
            int n = nt * 16 + q * 4 + reg;
            S2[n * 72 + col] = (f16)sigmoidf_(aq[reg]);
            S3[n * 72 + col] = (f16)sigmoidf_(akk[reg]);
          }
        }
      }
      if (t < 256) denomS[t] = 0.0f;
    }
    __syncthreads();

    f32x4 oacc[2][4] = {};
    const f16* Wv = Wsm + (size_t)((l == 1) ? 2 : 5) * 4096;  // unused for l==0

    #pragma unroll 1
    for (int ch = 0; ch < 4; ch++) {
      int m0 = ch * 64;
      if (l > 0) {
        // V-chunk projection: Vc[r][m] = sigmoid( sum_s Av[r][s] * M^T[m0+m][s] )
        #pragma unroll
        for (int i = 0; i < 2; i++) {
          int id = 2 * w + i, rt = id >> 2, mt = id & 3;
          int r = rt * 16 + l15;
          f16x8 a0 = *(const f16x8*)(Wv + r * 64 + q * 8);
          f16x8 a1 = *(const f16x8*)(Wv + r * 64 + 32 + q * 8);
          int brow = (m0 + mt * 16 + l15) * 72;
          f16x8 b0 = *(const f16x8*)&S1[brow + q * 8];
          f16x8 b1 = *(const f16x8*)&S1[brow + 32 + q * 8];
          f32x4 a = {}; a = MFMA(a0, b0, a); a = MFMA(a1, b1, a);
          int col = mt * 16 + l15;
          #pragma unroll
          for (int reg = 0; reg < 4; reg++)
            S5[(rt * 16 + q * 4 + reg) * 72 + col] = (f16)sigmoidf_(a[reg]);
        }
      }
      // S-chunk: S[n][m] = Q^T[n][:] . K^T[m0+m][:]; A = exp(S * sinv) -> S4
      #pragma unroll
      for (int half = 0; half < 2; half++) {
        int nt = 2 * w + half;
        int arow = (nt * 16 + l15) * 72;
        f16x8 af0 = *(const f16x8*)&S2[arow + q * 8];
        f16x8 af1 = *(const f16x8*)&S2[arow + 32 + q * 8];
        #pragma unroll
        for (int mt = 0; mt < 4; mt++) {
          int brow = (m0 + mt * 16 + l15) * 72;
          f16x8 b0 = *(const f16x8*)&S3[brow + q * 8];
          f16x8 b1 = *(const f16x8*)&S3[brow + 32 + q * 8];
          f32x4 a = {}; a = MFMA(af0, b0, a); a = MFMA(af1, b1, a);
          int col = mt * 16 + l15;
          #pragma unroll
          for (int reg = 0; reg < 4; reg++) {
            float e = __expf(a[reg] * sinv);
            S4[(nt * 16 + q * 4 + reg) * 72 + col] = (f16)e;
          }
        }
      }
      __syncthreads();
      // denominator accumulation (reads the same rounded f16 A as the GEMM)
      if (t < 256) {
        float s = 0.0f;
        const f16* row = &S4[t * 72];
        #pragma unroll
        for (int jj = 0; jj < 8; jj++) {
          f16x8 v = *(const f16x8*)(row + jj * 8);
          s += (float)v[0] + (float)v[1] + (float)v[2] + (float)v[3]
             + (float)v[4] + (float)v[5] + (float)v[6] + (float)v[7];
        }
        denomS[t] += s;
      }
      // o^T[n][r] += A[n][m] * V[r][m]
      {
        f16x8 vb[4][2];
        #pragma unroll
        for (int rt = 0; rt < 4; rt++) {
          int r = rt * 16 + l15;
          if (l == 0) {
            vb[rt][0] = *(const f16x8*)&S1[r * 264 + m0 + q * 8];
            vb[rt][1] = *(const f16x8*)&S1[r * 264 + m0 + 32 + q * 8];
          } else {
            vb[rt][0] = *(const f16x8*)&S5[r * 72 + q * 8];
            vb[rt][1] = *(const f16x8*)&S5[r * 72 + 32 + q * 8];
          }
        }
        #pragma unroll
        for (int half = 0; half < 2; half++) {
          int nt = 2 * w + half;
          int arow = (nt * 16 + l15) * 72;
          f16x8 af0 = *(const f16x8*)&S4[arow + q * 8];
          f16x8 af1 = *(const f16x8*)&S4[arow + 32 + q * 8];
          #pragma unroll
          for (int rt = 0; rt < 4; rt++) {
            oacc[half][rt] = MFMA(af0, vb[rt][0], oacc[half][rt]);
            oacc[half][rt] = MFMA(af1, vb[rt][1], oacc[half][rt]);
          }
        }
      }
      __syncthreads();
    } // chunks

    // normalize o and write o^T to S2 (Q^T dead)
    #pragma unroll
    for (int half = 0; half < 2; half++) {
      int nt = 2 * w + half;
      #pragma unroll
      for (int rt = 0; rt < 4; rt++) {
        int col = rt * 16 + l15;
        #pragma unroll
        for (int reg = 0; reg < 4; reg++) {
          int n = nt * 16 + q * 4 + reg;
          S2[n * 72 + col] = (f16)(oacc[half][rt][reg] / denomS[n]);
        }
      }
    }
    __syncthreads();
    // M^T[n][s] = silu( sum_r o^T[n][r] * Wo[s][r] ) -> S1
    {
      const f16* Wo = Wsm + (size_t)((l == 0) ? 6 : (l == 1) ? 7 : 8) * 4096;
      f16x8 bo[4][2];
      #pragma unroll
      for (int st = 0; st < 4; st++) {
        int s = st * 16 + l15;
        bo[st][0] = *(const f16x8*)(Wo + s * 64 + q * 8);
        bo[st][1] = *(const f16x8*)(Wo + s * 64 + 32 + q * 8);
      }
      #pragma unroll
      for (int half = 0; half < 2; half++) {
        int nt = 2 * w + half;
        int arow = (nt * 16 + l15) * 72;
        f16x8 af0 = *(const f16x8*)&S2[arow + q * 8];
        f16x8 af1 = *(const f16x8*)&S2[arow + 32 + q * 8];
        #pragma unroll
        for (int st = 0; st < 4; st++) {
          f32x4 a = {}; a = MFMA(af0, bo[st][0], a); a = MFMA(af1, bo[st][1], a);
          int col = st * 16 + l15;
          #pragma unroll
          for (int reg = 0; reg < 4; reg++) {
            float z = a[reg];
            S1[(nt * 16 + q * 4 + reg) * 72 + col] = (f16)(z * sigmoidf_(z));
          }
        }
      }
    }
    __syncthreads();
  } // layers

  // final reduction: Mf^T in S1 [n][h]
  float contrib = 0.0f;
  if (t < 256) {
    int n = t;
    const f16* row = &S1[n * 72];
    float d[4] = {0, 0, 0, 0}, pp = 0.0f;
    #pragma unroll
    for (int g = 0; g < 8; g++) {
      f16x8 v = *(const f16x8*)(row + g * 8);
      float ss = 0.0f;
      #pragma unroll
      for (int k = 0; k < 8; k++) { float f = (float)v[k]; ss += f * f; }
      if (g < 4) d[g] = ss; else pp += ss;
    }
    const float* xb = x + (size_t)b * 524288 + (size_t)((n & 1) * 2) * 256;
    int np = n >> 1;
    float q1a = xb[np], q1b = xb[256 + np];
    float q2a = xb[128 + np], q2b = xb[256 + 128 + np];
    contrib = d[0] * (q1a * q1a + q1b * q1b)
            + (d[1] + d[2]) * (q1a * q2a + q1b * q2b)
            + d[3] * (q2a * q2a + q2b * q2b) + pp;
  }
  #pragma unroll
  for (int off = 32; off; off >>= 1) contrib += __shfl_down(contrib, off);
  if (lane == 0) red[w] = contrib;
  __syncthreads();
  if (t == 0) {
    float s = 0.0f;
    #pragma unroll
    for (int i = 0; i < 8; i++) s += red[i];
    out[b] = s;
  }
}

// ---------------------------------------------------------------------------
extern "C" void kernel_launch(void* const* d_in, const int* in_sizes, int n_in,
                              void* d_out, int out_size, void* d_ws, size_t ws_size,
                              hipStream_t stream) {
  const float* x   = (const float*)d_in[0];
  const float* L   = (const float*)d_in[1];
  const float* Aq  = (const float*)d_in[2];
  const float* Ak  = (const float*)d_in[3];
  const float* Av  = (const float*)d_in[4];
  const float* Aq1 = (const float*)d_in[5];
  const float* Ak1 = (const float*)d_in[6];
  const float* Av1 = (const float*)d_in[7];
  const float* Aq5 = (const float*)d_in[8];
  const float* Ak5 = (const float*)d_in[9];
  const float* Av5 = (const float*)d_in[10];
  const float* Ao  = (const float*)d_in[11];
  const float* Ao1 = (const float*)d_in[12];
  const float* Ao5 = (const float*)d_in[13];

  char* ws = (char*)d_ws;
  float* scale = (float*)ws;                         // 256 B
  f16* Wcat = (f16*)(ws + 256);                      // 192*2048*2 = 786432
  f16* Wsm  = (f16*)(ws + 256 + 786432);             // 9*4096*2  = 73728
  f16* Qtg  = (f16*)(ws + 860416);                   // 64*256*64*2 = 2 MB
  f16* Ktg  = (f16*)(ws + 860416 + 2097152);
  f16* Vgg  = (f16*)(ws + 860416 + 2 * 2097152);
  float* out = (float*)d_out;

  prep_kernel<<<169, 256, 0, stream>>>(L, Aq, Ak, Av, Aq1, Ak1, Av1,
                                       Aq5, Ak5, Av5, Ao, Ao1, Ao5, scale, Wcat, Wsm);
  qkv1_kernel<<<dim3(4, 64), 256, 0, stream>>>(x, Wcat, Qtg, Ktg, Vgg);
  attn_kernel<<<64, 512, 0, stream>>>(x, scale, Wsm, Qtg, Ktg, Vgg, out);
}

// Round 2
// 272.110 us; speedup vs baseline: 1.0825x; 1.0825x over previous
//
#include <hip/hip_runtime.h>
#include <stdint.h>

typedef _Float16 f16;
typedef f16 f16x8 __attribute__((ext_vector_type(8)));
typedef float f32x4 __attribute__((ext_vector_type(4)));

#define MFMA(a,b,c) __builtin_amdgcn_mfma_f32_16x16x32_f16(a, b, c, 0, 0, 0)

__device__ __forceinline__ float sigmoidf_(float z) { return 1.0f / (1.0f + __expf(-z)); }

// ---------------------------------------------------------------------------
// prep: scale[b]; weights -> f16; zero out[0..63].
// Wcat = [Aq;Ak;Av] (192x2048). Wsm = 9 x (64x64): Aq1,Ak1,Av1,Aq5,Ak5,Av5,Ao,Ao1,Ao5
// ---------------------------------------------------------------------------
__global__ void prep_kernel(const float* __restrict__ L,
    const float* __restrict__ Aq, const float* __restrict__ Ak, const float* __restrict__ Av,
    const float* __restrict__ Aq1, const float* __restrict__ Ak1, const float* __restrict__ Av1,
    const float* __restrict__ Aq5, const float* __restrict__ Ak5, const float* __restrict__ Av5,
    const float* __restrict__ Ao, const float* __restrict__ Ao1, const float* __restrict__ Ao5,
    float* __restrict__ scale, f16* __restrict__ Wcat, f16* __restrict__ Wsm,
    float* __restrict__ out)
{
  __shared__ float r4[4];
  int blk = blockIdx.x, t = threadIdx.x;
  if (blk < 64) {
    float v = (L[blk * 512 + t] >= 1.0f) ? 1.0f : 0.0f;
    #pragma unroll
    for (int off = 32; off; off >>= 1) v += __shfl_down(v, off);
    if ((t & 63) == 0) r4[t >> 6] = v;
    __syncthreads();
    if (t == 0) scale[blk] = sqrtf(r4[0] + r4[1] + r4[2] + r4[3] + 1.0f);
  } else if (blk < 160) {
    int base = (blk - 64) * 4096;
    for (int i = 0; i < 16; i++) {
      int idx = base + t + i * 256;
      int row = idx >> 11, col = idx & 2047;
      float v = (row < 64) ? Aq[row * 2048 + col]
              : (row < 128) ? Ak[(row - 64) * 2048 + col]
              : Av[(row - 128) * 2048 + col];
      Wcat[idx] = (f16)v;
    }
  } else if (blk < 169) {
    int j = blk - 160;
    const float* s = (j == 0) ? Aq1 : (j == 1) ? Ak1 : (j == 2) ? Av1 : (j == 3) ? Aq5
                   : (j == 4) ? Ak5 : (j == 5) ? Av5 : (j == 6) ? Ao : (j == 7) ? Ao1 : Ao5;
    for (int i = 0; i < 16; i++) { int idx = t + i * 256; Wsm[j * 4096 + idx] = (f16)s[idx]; }
  } else {
    if (t < 64) out[t] = 0.0f;
  }
}

// ---------------------------------------------------------------------------
// qkv1: per (b, n-group of 32): Out[n][r] = sigmoid( sum_f x[b,f,n]*Wcat[r,f] )
// r: 0-63 -> Qt[b][n][r], 64-127 -> Kt[b][n][r-64], 128-191 -> V[b][r-128][n]
// grid (8,64) = 512 blocks -> 2 blocks/CU, 8 waves/CU for latency hiding.
// ---------------------------------------------------------------------------
__global__ __launch_bounds__(256) void qkv1_kernel(const float* __restrict__ x,
    const f16* __restrict__ Wcat, f16* __restrict__ Qt, f16* __restrict__ Kt,
    f16* __restrict__ Vg)
{
  int b = blockIdx.y, n0 = blockIdx.x * 32;
  int t = threadIdx.x, lane = t & 63, w = t >> 6;
  int l15 = lane & 15, q = lane >> 4;
  __shared__ f16 xt[32 * 72];    // x^T tile [n][f]
  __shared__ f16 wt[192 * 72];   // W tile [r][f]
  f32x4 acc[2][3] = {};
  const float* xb = x + (size_t)b * 524288 + n0;
  int tn = t & 31, fg = t >> 5;

  for (int f0 = 0; f0 < 2048; f0 += 64) {
    #pragma unroll
    for (int rep = 0; rep < 4; rep++) {
      int fl = fg * 8 + rep * 2;
      float a0 = xb[(size_t)(f0 + fl) * 256 + tn];
      float a1 = xb[(size_t)(f0 + fl + 1) * 256 + tn];
      uint32_t pk = (uint32_t)__builtin_bit_cast(uint16_t, (f16)a0)
                  | ((uint32_t)__builtin_bit_cast(uint16_t, (f16)a1) << 16);
      *(uint32_t*)&xt[tn * 72 + fl] = pk;
    }
    #pragma unroll
    for (int i = 0; i < 6; i++) {
      int id = t + i * 256, r = id >> 3, c = id & 7;
      *(uint4*)&wt[r * 72 + c * 8] = *(const uint4*)(Wcat + (size_t)r * 2048 + f0 + c * 8);
    }
    __syncthreads();
    #pragma unroll
    for (int ks = 0; ks < 2; ks++) {
      int k0 = ks * 32 + q * 8;
      f16x8 af[2], bf[3];
      af[0] = *(const f16x8*)&xt[l15 * 72 + k0];
      af[1] = *(const f16x8*)&xt[(16 + l15) * 72 + k0];
      #pragma unroll
      for (int j = 0; j < 3; j++) bf[j] = *(const f16x8*)&wt[((w * 3 + j) * 16 + l15) * 72 + k0];
      #pragma unroll
      for (int nt = 0; nt < 2; nt++)
        #pragma unroll
        for (int j = 0; j < 3; j++)
          acc[nt][j] = MFMA(af[nt], bf[j], acc[nt][j]);
    }
    __syncthreads();
  }
  #pragma unroll
  for (int nt = 0; nt < 2; nt++)
    #pragma unroll
    for (int j = 0; j < 3; j++) {
      int rr = (w * 3 + j) * 16 + l15;
      float s[4];
      #pragma unroll
      for (int reg = 0; reg < 4; reg++) s[reg] = sigmoidf_(acc[nt][j][reg]);
      int nbase = n0 + nt * 16 + q * 4;
      if (rr < 64) {
        #pragma unroll
        for (int reg = 0; reg < 4; reg++)
          Qt[(size_t)b * 16384 + (size_t)(nbase + reg) * 64 + rr] = (f16)s[reg];
      } else if (rr < 128) {
        #pragma unroll
        for (int reg = 0; reg < 4; reg++)
          Kt[(size_t)b * 16384 + (size_t)(nbase + reg) * 64 + (rr - 64)] = (f16)s[reg];
      } else {
        union { f16 h[4]; uint2 u; } pk;
        #pragma unroll
        for (int reg = 0; reg < 4; reg++) pk.h[reg] = (f16)s[reg];
        *(uint2*)(Vg + (size_t)b * 16384 + (size_t)(rr - 128) * 256 + nbase) = pk.u;
      }
    }
}

// ---------------------------------------------------------------------------
// attnB<LAYER>: grid (4,64), 512 threads (8 waves). Block (g,b) owns query
// rows n0=g*64..n0+63. Full K^T/V (all 256 cols) in LDS (K/V recomputed 4x
// for l>0). No chunking: S is [64][256]. LDS ~126 KB.
// Layouts: KT [256][72], SM = M^T [256][72] (l>0) then S4 [64][264],
// VM [64][264], QT [64][72] (later M' staging [64][64]), OT [64][72].
// ---------------------------------------------------------------------------
template<int LAYER>
__global__ __launch_bounds__(512) void attnB_kernel(const float* __restrict__ x,
    const float* __restrict__ scale, const f16* __restrict__ Wsm,
    const f16* __restrict__ Qtg, const f16* __restrict__ Ktg, const f16* __restrict__ Vgg,
    const f16* __restrict__ Min, f16* __restrict__ Mout, float* __restrict__ out)
{
  int g = blockIdx.x, b = blockIdx.y, n0 = g * 64;
  int t = threadIdx.x, lane = t & 63, w = t >> 6;
  int l15 = lane & 15, q = lane >> 4;
  __shared__ f16 KT[256 * 72];
  __shared__ f16 SM[256 * 72];
  __shared__ f16 VM[64 * 264];
  __shared__ f16 QT[64 * 72];
  __shared__ f16 OT[64 * 72];
  __shared__ float denomS[64];

  float sinv = 1.0f / scale[b];
  if (t < 64) denomS[t] = 0.0f;

  if (LAYER == 0) {
    const uint4* qs = (const uint4*)(Qtg + (size_t)b * 16384 + (size_t)n0 * 64);
    { int n = t >> 3, c = t & 7; *(uint4*)&QT[n * 72 + c * 8] = qs[t]; }
    const uint4* ks = (const uint4*)(Ktg + (size_t)b * 16384);
    const uint4* vs = (const uint4*)(Vgg + (size_t)b * 16384);
    #pragma unroll
    for (int i = 0; i < 4; i++) {
      int id = t + i * 512;
      int m = id >> 3, c = id & 7;
      *(uint4*)&KT[m * 72 + c * 8] = ks[id];
      int r = id >> 5, c2 = id & 31;
      *(uint4*)&VM[r * 264 + c2 * 8] = vs[id];
    }
  } else {
    const uint4* ms = (const uint4*)(Min + (size_t)b * 16384);
    #pragma unroll
    for (int i = 0; i < 4; i++) {
      int id = t + i * 512, m = id >> 3, c = id & 7;
      *(uint4*)&SM[m * 72 + c * 8] = ms[id];
    }
  }
  __syncthreads();

  const f16* Wq = Wsm + (size_t)(LAYER == 1 ? 0 : 3) * 4096;
  const f16* Wk = Wsm + (size_t)(LAYER == 1 ? 1 : 4) * 4096;
  const f16* Wv = Wsm + (size_t)(LAYER == 1 ? 2 : 5) * 4096;
  const f16* Wo = Wsm + (size_t)(LAYER == 0 ? 6 : (LAYER == 1 ? 7 : 8)) * 4096;

  if (LAYER > 0) {
    if (w < 4) {
      // KT[m][r] = sigmoid( sum_s M^T[m][s] * Wk[r][s] ), mt = w*4..w*4+3
      f16x8 bk[4][2];
      #pragma unroll
      for (int rt = 0; rt < 4; rt++) {
        bk[rt][0] = *(const f16x8*)(Wk + (rt * 16 + l15) * 64 + q * 8);
        bk[rt][1] = *(const f16x8*)(Wk + (rt * 16 + l15) * 64 + 32 + q * 8);
      }
      #pragma unroll
      for (int mi = 0; mi < 4; mi++) {
        int mt = w * 4 + mi;
        f16x8 a0 = *(const f16x8*)&SM[(mt * 16 + l15) * 72 + q * 8];
        f16x8 a1 = *(const f16x8*)&SM[(mt * 16 + l15) * 72 + 32 + q * 8];
        #pragma unroll
        for (int rt = 0; rt < 4; rt++) {
          f32x4 acc = {}; acc = MFMA(a0, bk[rt][0], acc); acc = MFMA(a1, bk[rt][1], acc);
          #pragma unroll
          for (int reg = 0; reg < 4; reg++)
            KT[(mt * 16 + q * 4 + reg) * 72 + rt * 16 + l15] = (f16)sigmoidf_(acc[reg]);
        }
      }
    } else {
      // VM[r][m] = sigmoid( sum_s Wv[r][s] * M^T[m][s] ), mt = (w-4)*4..
      f16x8 av[4][2];
      #pragma unroll
      for (int rt = 0; rt < 4; rt++) {
        av[rt][0] = *(const f16x8*)(Wv + (rt * 16 + l15) * 64 + q * 8);
        av[rt][1] = *(const f16x8*)(Wv + (rt * 16 + l15) * 64 + 32 + q * 8);
      }
      #pragma unroll
      for (int mi = 0; mi < 4; mi++) {
        int mt = (w - 4) * 4 + mi;
        f16x8 b0 = *(const f16x8*)&SM[(mt * 16 + l15) * 72 + q * 8];
        f16x8 b1 = *(const f16x8*)&SM[(mt * 16 + l15) * 72 + 32 + q * 8];
        #pragma unroll
        for (int rt = 0; rt < 4; rt++) {
          f32x4 acc = {}; acc = MFMA(av[rt][0], b0, acc); acc = MFMA(av[rt][1], b1, acc);
          #pragma unroll
          for (int reg = 0; reg < 4; reg++)
            VM[(rt * 16 + q * 4 + reg) * 264 + mt * 16 + l15] = (f16)sigmoidf_(acc[reg]);
        }
      }
    }
    // QT[n][r] for local rows: nt = w>>1, rt = (w&1)*2 + {0,1}
    {
      int nt = w >> 1;
      f16x8 a0 = *(const f16x8*)&SM[(n0 + nt * 16 + l15) * 72 + q * 8];
      f16x8 a1 = *(const f16x8*)&SM[(n0 + nt * 16 + l15) * 72 + 32 + q * 8];
      #pragma unroll
      for (int j = 0; j < 2; j++) {
        int rt = (w & 1) * 2 + j;
        f16x8 b0 = *(const f16x8*)(Wq + (rt * 16 + l15) * 64 + q * 8);
        f16x8 b1 = *(const f16x8*)(Wq + (rt * 16 + l15) * 64 + 32 + q * 8);
        f32x4 acc = {}; acc = MFMA(a0, b0, acc); acc = MFMA(a1, b1, acc);
        #pragma unroll
        for (int reg = 0; reg < 4; reg++)
          QT[(nt * 16 + q * 4 + reg) * 72 + rt * 16 + l15] = (f16)sigmoidf_(acc[reg]);
      }
    }
    __syncthreads();
  }

  // S = exp(QK^T * sinv): wave w -> nt = w>>1, mt = (w&1)*8 .. +7; denom via shfl+LDS atomic
  {
    int nt = w >> 1;
    f16x8 a0 = *(const f16x8*)&QT[(nt * 16 + l15) * 72 + q * 8];
    f16x8 a1 = *(const f16x8*)&QT[(nt * 16 + l15) * 72 + 32 + q * 8];
    float dsum[4] = {0.f, 0.f, 0.f, 0.f};
    #pragma unroll
    for (int mi = 0; mi < 8; mi++) {
      int mt = (w & 1) * 8 + mi;
      f16x8 b0 = *(const f16x8*)&KT[(mt * 16 + l15) * 72 + q * 8];
      f16x8 b1 = *(const f16x8*)&KT[(mt * 16 + l15) * 72 + 32 + q * 8];
      f32x4 acc = {}; acc = MFMA(a0, b0, acc); acc = MFMA(a1, b1, acc);
      #pragma unroll
      for (int reg = 0; reg < 4; reg++) {
        float e = __expf(acc[reg] * sinv);
        dsum[reg] += e;
        SM[(nt * 16 + q * 4 + reg) * 264 + mt * 16 + l15] = (f16)e;
      }
    }
    #pragma unroll
    for (int reg = 0; reg < 4; reg++) {
      #pragma unroll
      for (int mask = 1; mask < 16; mask <<= 1) dsum[reg] += __shfl_xor(dsum[reg], mask);
    }
    if (l15 == 0) {
      #pragma unroll
      for (int reg = 0; reg < 4; reg++) atomicAdd(&denomS[nt * 16 + q * 4 + reg], dsum[reg]);
    }
  }
  __syncthreads();

  // AV: o^T[n][r] = sum_m S4[n][m] VM[r][m]; normalize by denom -> OT
  {
    int nt = w >> 1;
    f32x4 oacc[2] = {};
    #pragma unroll
    for (int kc = 0; kc < 8; kc++) {
      f16x8 af = *(const f16x8*)&SM[(nt * 16 + l15) * 264 + kc * 32 + q * 8];
      #pragma unroll
      for (int j = 0; j < 2; j++) {
        int rt = (w & 1) * 2 + j;
        f16x8 bf = *(const f16x8*)&VM[(rt * 16 + l15) * 264 + kc * 32 + q * 8];
        oacc[j] = MFMA(af, bf, oacc[j]);
      }
    }
    #pragma unroll
    for (int j = 0; j < 2; j++) {
      int rt = (w & 1) * 2 + j;
      #pragma unroll
      for (int reg = 0; reg < 4; reg++) {
        int row = nt * 16 + q * 4 + reg;
        OT[row * 72 + rt * 16 + l15] = (f16)(oacc[j][reg] / denomS[row]);
      }
    }
  }
  __syncthreads();

  // M'[n][s] = silu( sum_r OT[n][r] Wo[s][r] ) -> Mst (QT reused, stride 64)
  f16* Mst = QT;
  {
    int nt = w >> 1;
    f16x8 a0 = *(const f16x8*)&OT[(nt * 16 + l15) * 72 + q * 8];
    f16x8 a1 = *(const f16x8*)&OT[(nt * 16 + l15) * 72 + 32 + q * 8];
    #pragma unroll
    for (int j = 0; j < 2; j++) {
      int st = (w & 1) * 2 + j;
      f16x8 b0 = *(const f16x8*)(Wo + (st * 16 + l15) * 64 + q * 8);
      f16x8 b1 = *(const f16x8*)(Wo + (st * 16 + l15) * 64 + 32 + q * 8);
      f32x4 acc = {}; acc = MFMA(a0, b0, acc); acc = MFMA(a1, b1, acc);
      #pragma unroll
      for (int reg = 0; reg < 4; reg++) {
        float z = acc[reg];
        Mst[(nt * 16 + q * 4 + reg) * 64 + st * 16 + l15] = (f16)(z * sigmoidf_(z));
      }
    }
  }
  __syncthreads();

  if (LAYER < 2) {
    int row = t >> 3, c = t & 7;
    *(uint4*)(Mout + (size_t)b * 16384 + (size_t)(n0 + row) * 64 + c * 8)
        = *(const uint4*)&Mst[row * 64 + c * 8];
  } else {
    float contrib = 0.0f;
    if (t < 64) {
      int ntok = n0 + t;
      const f16* row = &Mst[t * 64];
      float d[4] = {0, 0, 0, 0}, pp = 0.0f;
      #pragma unroll
      for (int gg = 0; gg < 8; gg++) {
        f16x8 v = *(const f16x8*)(row + gg * 8);
        float ss = 0.0f;
        #pragma unroll
        for (int k = 0; k < 8; k++) { float f = (float)v[k]; ss += f * f; }
        if (gg < 4) d[gg] = ss; else pp += ss;
      }
      int np = ntok >> 1, c0 = (ntok & 1) * 2;
      const float* xb = x + (size_t)b * 524288 + (size_t)c0 * 256;
      float q1a = xb[np], q1b = xb[256 + np];
      float q2a = xb[128 + np], q2b = xb[384 + np];
      contrib = d[0] * (q1a * q1a + q1b * q1b)
              + (d[1] + d[2]) * (q1a * q2a + q1b * q2b)
              + d[3] * (q2a * q2a + q2b * q2b) + pp;
    }
    if (w == 0) {
      #pragma unroll
      for (int off = 32; off; off >>= 1) contrib += __shfl_down(contrib, off);
      if (lane == 0) atomicAdd(out + b, contrib);
    }
  }
}

// ---------------------------------------------------------------------------
extern "C" void kernel_launch(void* const* d_in, const int* in_sizes, int n_in,
                              void* d_out, int out_size, void* d_ws, size_t ws_size,
                              hipStream_t stream) {
  const float* x   = (const float*)d_in[0];
  const float* L   = (const float*)d_in[1];
  const float* Aq  = (const float*)d_in[2];
  const float* Ak  = (const float*)d_in[3];
  const float* Av  = (const float*)d_in[4];
  const float* Aq1 = (const float*)d_in[5];
  const float* Ak1 = (const float*)d_in[6];
  const float* Av1 = (const float*)d_in[7];
  const float* Aq5 = (const float*)d_in[8];
  const float* Ak5 = (const float*)d_in[9];
  const float* Av5 = (const float*)d_in[10];
  const float* Ao  = (const float*)d_in[11];
  const float* Ao1 = (const float*)d_in[12];
  const float* Ao5 = (const float*)d_in[13];

  char* ws = (char*)d_ws;
  float* scale = (float*)ws;
  f16* Wcat  = (f16*)(ws + 256);
  f16* Wsm   = (f16*)(ws + 786688);
  f16* Qtg   = (f16*)(ws + 860416);
  f16* Ktg   = (f16*)(ws + 2957568);
  f16* Vgg   = (f16*)(ws + 5054720);
  f16* MbufA = (f16*)(ws + 7151872);
  f16* MbufB = (f16*)(ws + 9249024);
  float* out = (float*)d_out;

  prep_kernel<<<170, 256, 0, stream>>>(L, Aq, Ak, Av, Aq1, Ak1, Av1,
                                       Aq5, Ak5, Av5, Ao, Ao1, Ao5, scale, Wcat, Wsm, out);
  qkv1_kernel<<<dim3(8, 64), 256, 0, stream>>>(x, Wcat, Qtg, Ktg, Vgg);
  attnB_kernel<0><<<dim3(4, 64), 512, 0, stream>>>(x, scale, Wsm, Qtg, Ktg, Vgg,
                                                   nullptr, MbufA, out);
  attnB_kernel<1><<<dim3(4, 64), 512, 0, stream>>>(x, scale, Wsm, Qtg, Ktg, Vgg,
                                                   MbufA, MbufB, out);
  attnB_kernel<2><<<dim3(4, 64), 512, 0, stream>>>(x, scale, Wsm, Qtg, Ktg, Vgg,
                                                   MbufB, nullptr, out);
}